// Round 5
// baseline (386.279 us; speedup 1.0000x reference)
//
#include <hip/hip_runtime.h>
#include <hip/hip_bf16.h>
#include <cstdint>
#include <cstddef>

#define N 4096
#define NN ((size_t)N * (size_t)N)

typedef int   int4v   __attribute__((ext_vector_type(4)));
typedef float float4v __attribute__((ext_vector_type(4)));

__device__ inline void async16(const void* g, void* lds) {
    __builtin_amdgcn_global_load_lds(
        (const __attribute__((address_space(1))) void*)g,
        (__attribute__((address_space(3))) void*)lds, 16, 0, 0);
}

// ---------------- kernel 1: FUSED mod + diag + build_A8 (64x64 tile pairs) ----------------
// Block owns the unordered tile pair {(I,J),(J,I)}, I<=J, 64x64 tiles.  256 threads:
// thread = (r = t>>2, q = t&3).  Load phase: 4x float4 per input per tile, 4-lane
// 64-B-contiguous groups.  Pack phase: thread emits 16 contiguous i8 bytes (int4
// store, 64-B contiguous per row) for each of the 8 output tiles.  All expressions
// keep the proven operand order:  A[r][c] = mod[r][c] + mod[c][r] - d[c]  (exact
// small integers);  mod = fmaf(hard, -2o, o), hard = (p+u >= 1)  [bit-exact].
__global__ __launch_bounds__(256) void fused_mod_build(
        const float* __restrict__ ori,
        const float* __restrict__ clp,
        const float* __restrict__ uu,
        float* __restrict__ out,
        signed char* __restrict__ A,
        signed char* __restrict__ AT,
        signed char* __restrict__ Aa,
        signed char* __restrict__ ATa,
        double* __restrict__ accs) {
    const int I = blockIdx.x, J = blockIdx.y;
    if (I > J) return;
    __shared__ float sm1[64][65];   // sm1[i][j] = mod[bi+i][bj+j]
    __shared__ float sm2[64][65];   // sm2[j][i] = mod[bj+j][bi+i]
    __shared__ float dI[64], dJ[64];
    const int t = threadIdx.x;      // 0..255
    const int r = t >> 2;           // 0..63
    const int q = t & 3;            // 0..3
    const int bi = I * 64, bj = J * 64;
    if (I == 0 && J == 0 && t < 2) accs[t] = 0.0;
    if (t < 128) {
        const int x = (t < 64) ? (bi + t) : (bj + (t - 64));
        const size_t off = (size_t)x * N + x;
        const float o = ori[off];
        const float hard = (clp[off] + uu[off] >= 1.0f) ? 1.0f : 0.0f;
        const float d = fmaf(hard, -2.0f * o, o);
        if (t < 64) dI[t] = d; else dJ[t - 64] = d;
    }
    // tile 1: rows bi..bi+63, cols bj..bj+63
    #pragma unroll
    for (int k = 0; k < 4; ++k) {
        const size_t off = (size_t)(bi + r) * N + bj + k * 16 + q * 4;
        const float4v o4 = *(const float4v*)(ori + off);
        const float4v p4 = *(const float4v*)(clp + off);
        const float4v u4 = *(const float4v*)(uu + off);
        float4v m;
        #pragma unroll
        for (int c = 0; c < 4; ++c) {
            const float hard = (p4[c] + u4[c] >= 1.0f) ? 1.0f : 0.0f;
            m[c] = fmaf(hard, -2.0f * o4[c], o4[c]);
            sm1[r][k * 16 + q * 4 + c] = m[c];
        }
        *(float4v*)(out + off) = m;
    }
    // tile 2: rows bj..bj+63, cols bi..bi+63 (same tile when I==J: identical
    // recompute, skip duplicate out-write)
    #pragma unroll
    for (int k = 0; k < 4; ++k) {
        const size_t off = (size_t)(bj + r) * N + bi + k * 16 + q * 4;
        const float4v o4 = *(const float4v*)(ori + off);
        const float4v p4 = *(const float4v*)(clp + off);
        const float4v u4 = *(const float4v*)(uu + off);
        float4v m;
        #pragma unroll
        for (int c = 0; c < 4; ++c) {
            const float hard = (p4[c] + u4[c] >= 1.0f) ? 1.0f : 0.0f;
            m[c] = fmaf(hard, -2.0f * o4[c], o4[c]);
            sm2[r][k * 16 + q * 4 + c] = m[c];
        }
        if (I != J) *(float4v*)(out + off) = m;
    }
    __syncthreads();
    // pack phase: thread covers row r, cols q*16 .. q*16+15 of each tile
    int pkA1[4], pkAa1[4], pkT1[4], pkTa1[4];
    int pkA2[4], pkAa2[4], pkT2[4], pkTa2[4];
    #pragma unroll
    for (int w = 0; w < 4; ++w) {
        int a1w = 0, aa1w = 0, t1w = 0, ta1w = 0;
        int a2w = 0, aa2w = 0, t2w = 0, ta2w = 0;
        #pragma unroll
        for (int k = 0; k < 4; ++k) {
            const int c = q * 16 + w * 4 + k;
            // A tile (I,J): mod[bi+r][bj+c] + mod[bj+c][bi+r] - d[bj+c]
            const float a1 = sm1[r][c] + sm2[c][r] - dJ[c];
            const int v1 = (int)a1;  const int u1 = v1 < 0 ? -v1 : v1;
            a1w  |= (v1 & 255) << (8 * k);
            aa1w |= (u1 & 255) << (8 * k);
            // AT tile (J,I): A[bi+c][bj+r] = mod[bi+c][bj+r]+mod[bj+r][bi+c]-d[bj+r]
            const float t1 = sm1[c][r] + sm2[r][c] - dJ[r];
            const int w1 = (int)t1;  const int x1 = w1 < 0 ? -w1 : w1;
            t1w  |= (w1 & 255) << (8 * k);
            ta1w |= (x1 & 255) << (8 * k);
            // A tile (J,I): mod[bj+r][bi+c] + mod[bi+c][bj+r] - d[bi+c]
            const float a2 = sm2[r][c] + sm1[c][r] - dI[c];
            const int v2 = (int)a2;  const int u2 = v2 < 0 ? -v2 : v2;
            a2w  |= (v2 & 255) << (8 * k);
            aa2w |= (u2 & 255) << (8 * k);
            // AT tile (I,J): A[bj+c][bi+r] = mod[bj+c][bi+r]+mod[bi+r][bj+c]-d[bi+r]
            const float t2 = sm2[c][r] + sm1[r][c] - dI[r];
            const int w2 = (int)t2;  const int x2 = w2 < 0 ? -w2 : w2;
            t2w  |= (w2 & 255) << (8 * k);
            ta2w |= (x2 & 255) << (8 * k);
        }
        pkA1[w] = a1w; pkAa1[w] = aa1w; pkT1[w] = t1w; pkTa1[w] = ta1w;
        pkA2[w] = a2w; pkAa2[w] = aa2w; pkT2[w] = t2w; pkTa2[w] = ta2w;
    }
    const size_t oIJ = (size_t)(bi + r) * N + bj + q * 16;
    const size_t oJI = (size_t)(bj + r) * N + bi + q * 16;
    *(int4v*)&A  [oIJ] = *(int4v*)pkA1;
    *(int4v*)&Aa [oIJ] = *(int4v*)pkAa1;
    *(int4v*)&AT [oJI] = *(int4v*)pkT1;
    *(int4v*)&ATa[oJI] = *(int4v*)pkTa1;
    if (I != J) {
        *(int4v*)&A  [oJI] = *(int4v*)pkA2;
        *(int4v*)&Aa [oJI] = *(int4v*)pkAa2;
        *(int4v*)&AT [oIJ] = *(int4v*)pkT2;
        *(int4v*)&ATa[oIJ] = *(int4v*)pkTa2;
    }
}

// ---------------- kernel 4: i8 GEMM-trace, 256x256 tile, fine-grained LDS/MFMA interleave --
// One barrier per K-tile (proven schedule).  NEW: the 12 ds_read_b128 are ordered
// {af0[0], bf[0..3], af0[1..3], af1[0..3]} and the 32 MFMAs split into 8 groups of 4,
// each gated by a counted lgkmcnt (7,6,5,4,3,2,1,0) + sched_barrier(0) — the LDS pipe
// (~1150 cyc/tile/CU) streams underneath the matrix pipe (~1170 cyc/tile/CU) instead
// of serializing with it.
#define BK 64
#define NT (N / BK)      // 64 K-tiles
#define BUFSZ 32768      // A 16K + B 16K per buffer

__global__ __launch_bounds__(512, 2) void gemm_trace_i8(
        const signed char* __restrict__ Ag,
        const signed char* __restrict__ ATg,
        const signed char* __restrict__ Aag,
        const signed char* __restrict__ ATag,
        double* __restrict__ accs) {
    __shared__ __align__(16) signed char lds[4 * BUFSZ];   // 128 KiB
    __shared__ int red[8];
    const int z = blockIdx.z;
    const signed char* Asrc = z ? Aag  : Ag;    // M rows   (i-panel)
    const signed char* Bsrc = z ? ATag : ATg;   // MT rows  (k-panel), B[k][n] = MT[n][k]
    const int i0 = blockIdx.y * 256;
    const int k0 = blockIdx.x * 256;
    const int t = threadIdx.x;
    const int lane = t & 63;
    const int wave = t >> 6;        // 0..7
    const int wm = wave >> 2;       // 0..1 -> M offset wm*128
    const int wn = wave & 3;        // 0..3 -> N offset wn*64
    const int quad = lane >> 4;
    const int col  = lane & 15;

    const int c1 = t;
    const int r1 = c1 >> 2;          // 0..127
    const int r2 = r1 + 128;
    const int s1 = (((c1 & 3) ^ ((r1 >> 1) & 3)) << 4);
    const int s2 = (((c1 & 3) ^ ((r2 >> 1) & 3)) << 4);
    const signed char* gA1 = Asrc + (size_t)(i0 + r1) * N + s1;
    const signed char* gA2 = Asrc + (size_t)(i0 + r2) * N + s2;
    const signed char* gB1 = Bsrc + (size_t)(k0 + r1) * N + s1;
    const signed char* gB2 = Bsrc + (size_t)(k0 + r2) * N + s2;
    const int ldsA1 = (wave * 64) * 16;           // wave-uniform LDS bases
    const int ldsA2 = 8192  + (wave * 64) * 16;
    const int ldsB1 = 16384 + (wave * 64) * 16;
    const int ldsB2 = 24576 + (wave * 64) * 16;
    const int fsw = ((quad ^ ((col >> 1) & 3)) << 4);  // fragment k-slot after swizzle

    int4v acc[8][4];
    #pragma unroll
    for (int a = 0; a < 8; ++a)
        #pragma unroll
        for (int b = 0; b < 4; ++b)
            acc[a][b] = (int4v){0, 0, 0, 0};

    for (int p = 0; p < 3; ++p) {
        const int pb = p * BUFSZ;
        const size_t go = (size_t)p * BK;
        async16(gA1 + go, lds + pb + ldsA1);
        async16(gA2 + go, lds + pb + ldsA2);
        async16(gB1 + go, lds + pb + ldsB1);
        async16(gB2 + go, lds + pb + ldsB2);
    }
    asm volatile("s_waitcnt vmcnt(8)" ::: "memory");
    __builtin_amdgcn_s_barrier();
    __builtin_amdgcn_sched_barrier(0);

    for (int j = 0; j < NT; ++j) {
        const int buf = (j & 3) * BUFSZ;
        const signed char* Ab = lds + buf;
        const signed char* Bb = lds + buf + 16384;
        const int pre = j + 3;
        const size_t go = (size_t)pre * BK;
        const int pb = (pre & 3) * BUFSZ;
        int4v af0[4], af1[4], bf[4];
        // reads in gate order: af0[0], bf[0..3], af0[1..3], af1[0..3]
        af0[0] = *(const int4v*)(Ab + ((wm * 128 + 0 * 16 + col) << 6) + fsw);
        #pragma unroll
        for (int tc = 0; tc < 4; ++tc)
            bf[tc] = *(const int4v*)(Bb + ((wn * 64 + tc * 16 + col) << 6) + fsw);
        #pragma unroll
        for (int tr = 1; tr < 4; ++tr)
            af0[tr] = *(const int4v*)(Ab + ((wm * 128 + tr * 16 + col) << 6) + fsw);
        #pragma unroll
        for (int tr = 0; tr < 4; ++tr)
            af1[tr] = *(const int4v*)(Ab + ((wm * 128 + 64 + tr * 16 + col) << 6) + fsw);
        if (pre < NT) {
            async16(gA1 + go, lds + pb + ldsA1);
            async16(gA2 + go, lds + pb + ldsA2);
            async16(gB1 + go, lds + pb + ldsB1);
            async16(gB2 + go, lds + pb + ldsB2);
        }
        __builtin_amdgcn_s_setprio(1);
        // group 0: needs af0[0]+bf (first 5 reads) -> 7 outstanding allowed
        asm volatile("s_waitcnt lgkmcnt(7)" ::: "memory");
        __builtin_amdgcn_sched_barrier(0);
        #pragma unroll
        for (int tc = 0; tc < 4; ++tc)
            acc[0][tc] = __builtin_amdgcn_mfma_i32_16x16x64_i8(af0[0], bf[tc], acc[0][tc], 0, 0, 0);
        // groups 1-3: af0[1..3]
        #pragma unroll
        for (int tr = 1; tr < 4; ++tr) {
            if (tr == 1)      asm volatile("s_waitcnt lgkmcnt(6)" ::: "memory");
            else if (tr == 2) asm volatile("s_waitcnt lgkmcnt(5)" ::: "memory");
            else              asm volatile("s_waitcnt lgkmcnt(4)" ::: "memory");
            __builtin_amdgcn_sched_barrier(0);
            #pragma unroll
            for (int tc = 0; tc < 4; ++tc)
                acc[tr][tc] = __builtin_amdgcn_mfma_i32_16x16x64_i8(af0[tr], bf[tc], acc[tr][tc], 0, 0, 0);
        }
        // groups 4-7: af1[0..3]
        #pragma unroll
        for (int tr = 0; tr < 4; ++tr) {
            if (tr == 0)      asm volatile("s_waitcnt lgkmcnt(3)" ::: "memory");
            else if (tr == 1) asm volatile("s_waitcnt lgkmcnt(2)" ::: "memory");
            else if (tr == 2) asm volatile("s_waitcnt lgkmcnt(1)" ::: "memory");
            else              asm volatile("s_waitcnt lgkmcnt(0)" ::: "memory");
            __builtin_amdgcn_sched_barrier(0);
            #pragma unroll
            for (int tc = 0; tc < 4; ++tc)
                acc[4 + tr][tc] = __builtin_amdgcn_mfma_i32_16x16x64_i8(af1[tr], bf[tc], acc[4 + tr][tc], 0, 0, 0);
        }
        __builtin_amdgcn_s_setprio(0);
        if (j < NT - 3)       { asm volatile("s_waitcnt vmcnt(8)" ::: "memory"); }
        else if (j == NT - 3) { asm volatile("s_waitcnt vmcnt(4)" ::: "memory"); }
        else if (j == NT - 2) { asm volatile("s_waitcnt vmcnt(0)" ::: "memory"); }
        __builtin_amdgcn_s_barrier();
        __builtin_amdgcn_sched_barrier(0);
    }

    int part = 0;
    #pragma unroll
    for (int mr = 0; mr < 8; ++mr) {
        const int ib = i0 + wm * 128 + mr * 16 + quad * 4;
        #pragma unroll
        for (int tc = 0; tc < 4; ++tc) {
            const int kk = k0 + wn * 64 + tc * 16 + col;
            const int mv = *(const int*)&Asrc[(size_t)kk * N + ib];
            #pragma unroll
            for (int r = 0; r < 4; ++r)
                part += acc[mr][tc][r] * (int)(signed char)(mv >> (8 * r));
        }
    }
    #pragma unroll
    for (int off = 32; off > 0; off >>= 1)
        part += __shfl_down(part, off, 64);
    if (lane == 0) red[wave] = part;
    __syncthreads();
    if (t == 0) {
        int tot = 0;
        #pragma unroll
        for (int w = 0; w < 8; ++w) tot += red[w];
        atomicAdd(&accs[z], (double)tot);
    }
}

// ---------------- kernel 5: balance ----------------
__global__ void finalize_kernel(const double* __restrict__ accs, float* __restrict__ out) {
    out[NN] = (float)(0.5 * (1.0 + accs[0] / accs[1]));
}

extern "C" void kernel_launch(void* const* d_in, const int* in_sizes, int n_in,
                              void* d_out, int out_size, void* d_ws, size_t ws_size,
                              hipStream_t stream) {
    const float* ori = (const float*)d_in[0];
    const float* clp = (const float*)d_in[1];
    const float* u   = (const float*)d_in[2];
    float* out = (float*)d_out;
    char* ws = (char*)d_ws;
    signed char* A8   = (signed char*)ws;                    // 16 MiB
    signed char* AT8  = (signed char*)(ws + NN);             // 16 MiB
    signed char* Aa8  = (signed char*)(ws + 2 * NN);         // 16 MiB
    signed char* ATa8 = (signed char*)(ws + 3 * NN);         // 16 MiB
    double*      accs = (double*)(ws + 4 * NN);              // 16 B

    fused_mod_build<<<dim3(64, 64), 256, 0, stream>>>(
        ori, clp, u, out, A8, AT8, Aa8, ATa8, accs);
    gemm_trace_i8<<<dim3(N / 256, N / 256, 2), 512, 0, stream>>>(A8, AT8, Aa8, ATa8, accs);
    finalize_kernel<<<1, 1, 0, stream>>>(accs, out);
}